// Round 6
// baseline (466.422 us; speedup 1.0000x reference)
//
#include <hip/hip_runtime.h>
#include <hip/hip_bf16.h>

#define H 64

typedef __attribute__((ext_vector_type(8))) short short8;
typedef __attribute__((ext_vector_type(4))) float float4v;

__device__ __forceinline__ float lane_bcast(float v, int k) {
    return __int_as_float(__builtin_amdgcn_readlane(__float_as_int(v), k));
}
__device__ __forceinline__ short f2bf_bits(float f) {
    union { __hip_bfloat16 b; short s; } u;
    u.b = __float2bfloat16(f);
    return u.s;
}
__device__ __forceinline__ float bf2f(unsigned short s) {
    union { unsigned int u; float f; } v;
    v.u = ((unsigned int)s) << 16;
    return v.f;
}
// split 8 consecutive floats into bf16 hi + lo fragments
__device__ __forceinline__ void split8(const float* __restrict__ p,
                                       short8& hi, short8& lo) {
    float4v f0 = *(const float4v*)p;
    float4v f1 = *(const float4v*)(p + 4);
#pragma unroll
    for (int j = 0; j < 8; j++) {
        float f = (j < 4) ? f0[j] : f1[j - 4];
        short h = f2bf_bits(f);
        float fh = bf2f((unsigned short)h);
        hi[j] = h;
        lo[j] = f2bf_bits(f - fh);
    }
}
__device__ __forceinline__ void zero8(short8& hi, short8& lo) {
#pragma unroll
    for (int j = 0; j < 8; j++) { hi[j] = 0; lo[j] = 0; }
}

#define MFMA(a, b, c) __builtin_amdgcn_mfma_f32_16x16x32_bf16(a, b, c, 0, 0, 0)

// ---------------- weight fragment prep (once per call; shared by all waves) ----
// msg fragments: per round, 16 slots (tile 0..7 x ks 0..1); hi block then lo.
__global__ __launch_bounds__(64) void prep_msg(
    const float* __restrict__ msg_W, short* __restrict__ frag)
{
    const int slot = blockIdx.x & 15, t = blockIdx.x >> 4, lane = threadIdx.x;
    const int tile = slot >> 1, ks = slot & 1;
    const float* W = msg_W + (size_t)t * H * 129;
    const int wrow = (tile & 3) * 16 + (lane & 15);
    const int coff = (tile < 4) ? 0 : 64;
    const int kq = (lane >> 4) * 8;
    short8 hi, lo;
    split8(W + (size_t)wrow * 129 + coff + ks * 32 + kq, hi, lo);
    short8* out = (short8*)(frag + (size_t)t * 16384);
    out[slot * 64 + lane] = hi;
    out[16 * 64 + slot * 64 + lane] = lo;
}

// gru fragments: per round, 48 slots (tile 0..23 x ks 0..1); hi block then lo.
__global__ __launch_bounds__(64) void prep_gru(
    const float* __restrict__ Wih, const float* __restrict__ Whh,
    short* __restrict__ frag)
{
    const int slot = blockIdx.x % 48, t = blockIdx.x / 48, lane = threadIdx.x;
    const int tile = slot >> 1, ks = slot & 1;
    const int kq = (lane >> 4) * 8;
    const float* Wp = (tile < 12)
        ? (Wih + (size_t)t * 192 * H + ((size_t)(tile * 16 + (lane & 15))) * H)
        : (Whh + (size_t)t * 192 * H + ((size_t)((tile - 12) * 16 + (lane & 15))) * H);
    short8 hi, lo;
    split8(Wp + ks * 32 + kq, hi, lo);
    short8* out = (short8*)(frag + (size_t)t * 49152);
    out[slot * 64 + lane] = hi;
    out[48 * 64 + slot * 64 + lane] = lo;
}

// ---------------- count: deg[n] += 1, record local position --------------------
__global__ __launch_bounds__(256) void count_kernel(
    const int* __restrict__ row, int* __restrict__ deg,
    int* __restrict__ lpos, int E)
{
    int e = blockIdx.x * 256 + threadIdx.x;
    if (e < E) lpos[e] = atomicAdd(&deg[row[e]], 1);
}

// ---------------- 3-phase exclusive scan of deg -> offsets ---------------------
__global__ __launch_bounds__(256) void scan_block(
    const int* __restrict__ deg, int* __restrict__ offsets,
    int* __restrict__ block_sums, int N)
{
    __shared__ int s[256];
    int tid = threadIdx.x, gid = blockIdx.x * 256 + tid;
    int v = (gid < N) ? deg[gid] : 0;
    s[tid] = v; __syncthreads();
    for (int off = 1; off < 256; off <<= 1) {
        int t = (tid >= off) ? s[tid - off] : 0;
        __syncthreads();
        s[tid] += t;
        __syncthreads();
    }
    if (gid < N) offsets[gid] = s[tid] - v;   // exclusive
    if (tid == 255) block_sums[blockIdx.x] = s[255];
}

__global__ __launch_bounds__(512) void scan_sums(int* __restrict__ block_sums, int nb)
{
    __shared__ int s[512];
    int tid = threadIdx.x;
    int v = (tid < nb) ? block_sums[tid] : 0;
    s[tid] = v; __syncthreads();
    for (int off = 1; off < 512; off <<= 1) {
        int t = (tid >= off) ? s[tid - off] : 0;
        __syncthreads();
        s[tid] += t;
        __syncthreads();
    }
    if (tid < nb) block_sums[tid] = s[tid] - v;  // exclusive
}

__global__ __launch_bounds__(256) void scan_add(
    int* __restrict__ offsets, const int* __restrict__ block_sums, int N, int E)
{
    int gid = blockIdx.x * 256 + threadIdx.x;
    if (gid < N) offsets[gid] += block_sums[blockIdx.x];
    if (gid == 0) offsets[N] = E;
}

// ---------------- atomic-free CSR scatter --------------------------------------
__global__ __launch_bounds__(256) void scatter_kernel(
    const int* __restrict__ row, const int* __restrict__ col,
    const float* __restrict__ attr, const int* __restrict__ offsets,
    const int* __restrict__ lpos,
    int* __restrict__ col_sorted, float* __restrict__ attr_sorted, int E)
{
    int e = blockIdx.x * 256 + threadIdx.x;
    if (e < E) {
        int p = offsets[row[e]] + lpos[e];
        col_sorted[p] = col[e];
        attr_sorted[p] = attr[e];
    }
}

// ---------------- node transform (MFMA, quadrant split) ------------------------
// Block = 64 nodes (4 M-tiles); wave q computes col quadrant q of xd (tile q)
// and of agg (tile 4+q): xd = Wd*x, agg = deg*(Ws*x + b).
__global__ __launch_bounds__(256) void node_transform_mfma(
    const float* __restrict__ x, const short* __restrict__ frag,
    const float* __restrict__ b, const int* __restrict__ deg,
    float* __restrict__ xd, float* __restrict__ agg, int N)
{
    const int tid = threadIdx.x, lane = tid & 63, q = tid >> 6;
    const int base = blockIdx.x * 64;
    const int arow = lane & 15;
    const int kq = (lane >> 4) * 8;
    const short8* fhi = (const short8*)frag;
    const short8* flo = fhi + 16 * 64;

    float4v accd[4], accs[4];
#pragma unroll
    for (int mt = 0; mt < 4; mt++) {
        accd[mt] = (float4v){0.f, 0.f, 0.f, 0.f};
        accs[mt] = (float4v){0.f, 0.f, 0.f, 0.f};
    }

#pragma unroll
    for (int ks = 0; ks < 2; ks++) {
        short8 ah[4], al[4];
#pragma unroll
        for (int mt = 0; mt < 4; mt++) {
            int m = base + mt * 16 + arow;
            if (m < N) split8(x + (size_t)m * H + ks * 32 + kq, ah[mt], al[mt]);
            else       zero8(ah[mt], al[mt]);
        }
        const int sd = q * 2 + ks;            // tile q  (xd cols)
        short8 bh = fhi[sd * 64 + lane];
        short8 bl = flo[sd * 64 + lane];
#pragma unroll
        for (int mt = 0; mt < 4; mt++) {
            accd[mt] = MFMA(ah[mt], bh, accd[mt]);
            accd[mt] = MFMA(al[mt], bh, accd[mt]);
            accd[mt] = MFMA(ah[mt], bl, accd[mt]);
        }
        const int ss = (4 + q) * 2 + ks;      // tile 4+q (agg cols)
        short8 ch = fhi[ss * 64 + lane];
        short8 cl = flo[ss * 64 + lane];
#pragma unroll
        for (int mt = 0; mt < 4; mt++) {
            accs[mt] = MFMA(ah[mt], ch, accs[mt]);
            accs[mt] = MFMA(al[mt], ch, accs[mt]);
            accs[mt] = MFMA(ah[mt], cl, accs[mt]);
        }
    }

    const int colb = lane & 15;
    const int rq4 = (lane >> 4) * 4;
    const int j = q * 16 + colb;
    const float bj = b[j];
#pragma unroll
    for (int mt = 0; mt < 4; mt++) {
#pragma unroll
        for (int r = 0; r < 4; r++) {
            const int m = base + mt * 16 + rq4 + r;
            if (m >= N) continue;
            xd[(size_t)m * H + j] = accd[mt][r];
            agg[(size_t)m * H + j] = (float)deg[m] * (accs[mt][r] + bj);
        }
    }
}

// ---------------- gather aggregation (fp32 xd, 4-way ILP) -----------------------
// agg[n][j] += sum_e ( xd[col_e][j] + wa[j]*attr_e )
__global__ __launch_bounds__(256) void aggregate(
    const int* __restrict__ offsets, const int* __restrict__ col_sorted,
    const float* __restrict__ attr_sorted, const float* __restrict__ xd,
    const float* __restrict__ W, float* __restrict__ agg, int N)
{
    const int tid = threadIdx.x, lane = tid & 63, wv = tid >> 6;
    const int n = blockIdx.x * 4 + wv;
    if (n >= N) return;
    const float wa = W[(size_t)lane * 129 + 128];
    const int beg = offsets[n], end = offsets[n + 1];
    float acc0 = agg[(size_t)n * H + lane];
    float acc1 = 0.f, acc2 = 0.f, acc3 = 0.f;
    for (int k = beg; k < end; k += 64) {
        int cnt = end - k; if (cnt > 64) cnt = 64;
        int cl = 0; float al = 0.f;
        if (k + lane < end) {
            cl = col_sorted[k + lane];
            al = attr_sorted[k + lane];
        }
        int j = 0;
        for (; j + 4 <= cnt; j += 4) {
            int c0 = __builtin_amdgcn_readlane(cl, j);
            int c1 = __builtin_amdgcn_readlane(cl, j + 1);
            int c2 = __builtin_amdgcn_readlane(cl, j + 2);
            int c3 = __builtin_amdgcn_readlane(cl, j + 3);
            float a0 = lane_bcast(al, j);
            float a1 = lane_bcast(al, j + 1);
            float a2 = lane_bcast(al, j + 2);
            float a3 = lane_bcast(al, j + 3);
            float v0 = xd[(size_t)c0 * H + lane];
            float v1 = xd[(size_t)c1 * H + lane];
            float v2 = xd[(size_t)c2 * H + lane];
            float v3 = xd[(size_t)c3 * H + lane];
            acc0 += fmaf(wa, a0, v0);
            acc1 += fmaf(wa, a1, v1);
            acc2 += fmaf(wa, a2, v2);
            acc3 += fmaf(wa, a3, v3);
        }
        for (; j < cnt; j++) {
            int c = __builtin_amdgcn_readlane(cl, j);
            float a = lane_bcast(al, j);
            acc0 += fmaf(wa, a, xd[(size_t)c * H + lane]);
        }
    }
    agg[(size_t)n * H + lane] = (acc0 + acc1) + (acc2 + acc3);
}

// ---------------- GRU cell (MFMA, quadrant split) -------------------------------
// Block = 64 nodes (4 M-tiles); wave q computes gate cols q*16..q*16+15:
// gi tiles {q, 4+q, 8+q}, gh tiles {12+q, 16+q, 20+q}.
__global__ __launch_bounds__(256) void gru_mfma(
    const float* __restrict__ agg, float* __restrict__ x,
    const short* __restrict__ frag,
    const float* __restrict__ bih, const float* __restrict__ bhh, int N)
{
    const int tid = threadIdx.x, lane = tid & 63, q = tid >> 6;
    const int base = blockIdx.x * 64;
    const int arow = lane & 15;
    const int kq = (lane >> 4) * 8;
    const short8* fhi = (const short8*)frag;
    const short8* flo = fhi + 48 * 64;

    float4v acc[6][4];   // [ir,iz,in,hr,hz,hn][M-tile]
#pragma unroll
    for (int g = 0; g < 6; g++)
#pragma unroll
        for (int mt = 0; mt < 4; mt++) acc[g][mt] = (float4v){0.f, 0.f, 0.f, 0.f};

#pragma unroll
    for (int ks = 0; ks < 2; ks++) {
        short8 gah[4], gal[4], hh[4], hl[4];
#pragma unroll
        for (int mt = 0; mt < 4; mt++) {
            int m = base + mt * 16 + arow;
            if (m < N) {
                split8(agg + (size_t)m * H + ks * 32 + kq, gah[mt], gal[mt]);
                split8(x   + (size_t)m * H + ks * 32 + kq, hh[mt],  hl[mt]);
            } else { zero8(gah[mt], gal[mt]); zero8(hh[mt], hl[mt]); }
        }
#pragma unroll
        for (int g = 0; g < 3; g++) {
            const int si = (g * 4 + q) * 2 + ks;        // gi tile
            short8 bh = fhi[si * 64 + lane];
            short8 bl = flo[si * 64 + lane];
#pragma unroll
            for (int mt = 0; mt < 4; mt++) {
                acc[g][mt] = MFMA(gah[mt], bh, acc[g][mt]);
                acc[g][mt] = MFMA(gal[mt], bh, acc[g][mt]);
                acc[g][mt] = MFMA(gah[mt], bl, acc[g][mt]);
            }
            const int sh = (12 + g * 4 + q) * 2 + ks;   // gh tile
            short8 ch = fhi[sh * 64 + lane];
            short8 cl = flo[sh * 64 + lane];
#pragma unroll
            for (int mt = 0; mt < 4; mt++) {
                acc[3 + g][mt] = MFMA(hh[mt], ch, acc[3 + g][mt]);
                acc[3 + g][mt] = MFMA(hl[mt], ch, acc[3 + g][mt]);
                acc[3 + g][mt] = MFMA(hh[mt], cl, acc[3 + g][mt]);
            }
        }
    }

    // waves share nodes: all reads of x (A fragments) must precede any write
    __syncthreads();

    const int colb = lane & 15;
    const int rq4 = (lane >> 4) * 4;
    const int j = q * 16 + colb;
    const float b_ir = bih[j], b_iz = bih[64 + j], b_in = bih[128 + j];
    const float b_hr = bhh[j], b_hz = bhh[64 + j], b_hn = bhh[128 + j];
#pragma unroll
    for (int mt = 0; mt < 4; mt++) {
#pragma unroll
        for (int r = 0; r < 4; r++) {
            const int m = base + mt * 16 + rq4 + r;
            if (m >= N) continue;
            float ir = acc[0][mt][r] + b_ir;
            float iz = acc[1][mt][r] + b_iz;
            float in_ = acc[2][mt][r] + b_in;
            float hr = acc[3][mt][r] + b_hr;
            float hz = acc[4][mt][r] + b_hz;
            float hn = acc[5][mt][r] + b_hn;
            float rr = 1.f / (1.f + __expf(-(ir + hr)));
            float zz = 1.f / (1.f + __expf(-(iz + hz)));
            float e2 = __expf(2.f * (in_ + rr * hn));
            float nn = 1.f - 2.f / (e2 + 1.f);          // tanh
            float hold = x[(size_t)m * H + j];
            x[(size_t)m * H + j] = (1.f - zz) * nn + zz * hold;
        }
    }
}

extern "C" void kernel_launch(void* const* d_in, const int* in_sizes, int n_in,
                              void* d_out, int out_size, void* d_ws, size_t ws_size,
                              hipStream_t stream) {
    const float* x_in  = (const float*)d_in[0];
    const int*   ei    = (const int*)d_in[1];
    const float* attr  = (const float*)d_in[2];
    const float* msg_W = (const float*)d_in[3];
    const float* msg_b = (const float*)d_in[4];
    const float* Wih   = (const float*)d_in[5];
    const float* bih   = (const float*)d_in[6];
    const float* Whh   = (const float*)d_in[7];
    const float* bhh   = (const float*)d_in[8];

    const int N = in_sizes[0] / H;        // 100000
    const int E = in_sizes[2];            // 1250000
    const int T = in_sizes[4] / H;        // 2
    const int* row = ei;
    const int* col = ei + E;

    // ---- workspace layout ----
    float* x          = (float*)d_out;                    // live node state [N,H]
    float* agg        = (float*)d_ws;                     // [N,H]
    float* xd         = agg + (size_t)N * H;              // [N,H]
    int*   deg        = (int*)(xd + (size_t)N * H);       // [N]
    int*   offsets    = deg + N;                          // [N+1]
    int*   bsums      = offsets + (N + 1);                // [512]
    int*   lpos       = bsums + 512;                      // [E]
    int*   col_sorted = lpos + E;                         // [E]
    float* attr_sorted = (float*)(col_sorted + E);        // [E]
    short* msgfrag    = (short*)(attr_sorted + E);        // [T][16384]
    short* grufrag    = msgfrag + (size_t)T * 16384;      // [T][49152]

    const int nb = (N + 255) / 256;
    const int eb = (E + 255) / 256;

    hipMemcpyAsync(x, x_in, (size_t)N * H * sizeof(float),
                   hipMemcpyDeviceToDevice, stream);
    hipMemsetAsync(deg, 0, (size_t)N * sizeof(int), stream);

    prep_msg<<<T * 16, 64, 0, stream>>>(msg_W, msgfrag);
    prep_gru<<<T * 48, 64, 0, stream>>>(Wih, Whh, grufrag);

    count_kernel<<<eb, 256, 0, stream>>>(row, deg, lpos, E);
    scan_block<<<nb, 256, 0, stream>>>(deg, offsets, bsums, N);
    scan_sums<<<1, 512, 0, stream>>>(bsums, nb);
    scan_add<<<nb, 256, 0, stream>>>(offsets, bsums, N, E);
    scatter_kernel<<<eb, 256, 0, stream>>>(row, col, attr, offsets, lpos,
                                           col_sorted, attr_sorted, E);

    const int nbq = (N + 63) / 64;           // 64 nodes / block (4 waves)
    const int agg_blocks = (N + 3) / 4;      // 4 nodes (waves) / block

    for (int t = 0; t < T; t++) {
        const float* Wt = msg_W + (size_t)t * H * (2 * H + 1);
        node_transform_mfma<<<nbq, 256, 0, stream>>>(
            x, msgfrag + (size_t)t * 16384, msg_b + (size_t)t * H, deg, xd, agg, N);
        aggregate<<<agg_blocks, 256, 0, stream>>>(
            offsets, col_sorted, attr_sorted, xd, Wt, agg, N);
        gru_mfma<<<nbq, 256, 0, stream>>>(
            agg, x, grufrag + (size_t)t * 49152,
            bih + (size_t)t * 3 * H, bhh + (size_t)t * 3 * H, N);
    }
}

// Round 7
// 415.418 us; speedup vs baseline: 1.1228x; 1.1228x over previous
//
#include <hip/hip_runtime.h>
#include <hip/hip_bf16.h>

#define H 64

typedef __attribute__((ext_vector_type(8))) short short8;
typedef __attribute__((ext_vector_type(4))) float float4v;

__device__ __forceinline__ float lane_bcast(float v, int k) {
    return __int_as_float(__builtin_amdgcn_readlane(__float_as_int(v), k));
}
__device__ __forceinline__ short f2bf_bits(float f) {
    union { __hip_bfloat16 b; short s; } u;
    u.b = __float2bfloat16(f);
    return u.s;
}
__device__ __forceinline__ float bf2f(unsigned short s) {
    union { unsigned int u; float f; } v;
    v.u = ((unsigned int)s) << 16;
    return v.f;
}
// split 8 consecutive floats into bf16 hi + lo fragments
__device__ __forceinline__ void split8(const float* __restrict__ p,
                                       short8& hi, short8& lo) {
    float4v f0 = *(const float4v*)p;
    float4v f1 = *(const float4v*)(p + 4);
#pragma unroll
    for (int j = 0; j < 8; j++) {
        float f = (j < 4) ? f0[j] : f1[j - 4];
        short h = f2bf_bits(f);
        float fh = bf2f((unsigned short)h);
        hi[j] = h;
        lo[j] = f2bf_bits(f - fh);
    }
}
__device__ __forceinline__ void zero8(short8& hi, short8& lo) {
#pragma unroll
    for (int j = 0; j < 8; j++) { hi[j] = 0; lo[j] = 0; }
}

#define MFMA(a, b, c) __builtin_amdgcn_mfma_f32_16x16x32_bf16(a, b, c, 0, 0, 0)

// ---------------- weight fragment prep (once per call; shared by all waves) ----
__global__ __launch_bounds__(64) void prep_msg(
    const float* __restrict__ msg_W, short* __restrict__ frag)
{
    const int slot = blockIdx.x & 15, t = blockIdx.x >> 4, lane = threadIdx.x;
    const int tile = slot >> 1, ks = slot & 1;
    const float* W = msg_W + (size_t)t * H * 129;
    const int wrow = (tile & 3) * 16 + (lane & 15);
    const int coff = (tile < 4) ? 0 : 64;
    const int kq = (lane >> 4) * 8;
    short8 hi, lo;
    split8(W + (size_t)wrow * 129 + coff + ks * 32 + kq, hi, lo);
    short8* out = (short8*)(frag + (size_t)t * 16384);
    out[slot * 64 + lane] = hi;
    out[16 * 64 + slot * 64 + lane] = lo;
}

__global__ __launch_bounds__(64) void prep_gru(
    const float* __restrict__ Wih, const float* __restrict__ Whh,
    short* __restrict__ frag)
{
    const int slot = blockIdx.x % 48, t = blockIdx.x / 48, lane = threadIdx.x;
    const int tile = slot >> 1, ks = slot & 1;
    const int kq = (lane >> 4) * 8;
    const float* Wp = (tile < 12)
        ? (Wih + (size_t)t * 192 * H + ((size_t)(tile * 16 + (lane & 15))) * H)
        : (Whh + (size_t)t * 192 * H + ((size_t)((tile - 12) * 16 + (lane & 15))) * H);
    short8 hi, lo;
    split8(Wp + ks * 32 + kq, hi, lo);
    short8* out = (short8*)(frag + (size_t)t * 49152);
    out[slot * 64 + lane] = hi;
    out[48 * 64 + slot * 64 + lane] = lo;
}

// ---------------- count: deg[n] += 1, record local position --------------------
__global__ __launch_bounds__(256) void count_kernel(
    const int* __restrict__ row, int* __restrict__ deg,
    int* __restrict__ lpos, int E)
{
    int e = blockIdx.x * 256 + threadIdx.x;
    if (e < E) lpos[e] = atomicAdd(&deg[row[e]], 1);
}

// ---------------- 3-phase exclusive scan of deg -> offsets ---------------------
__global__ __launch_bounds__(256) void scan_block(
    const int* __restrict__ deg, int* __restrict__ offsets,
    int* __restrict__ block_sums, int N)
{
    __shared__ int s[256];
    int tid = threadIdx.x, gid = blockIdx.x * 256 + tid;
    int v = (gid < N) ? deg[gid] : 0;
    s[tid] = v; __syncthreads();
    for (int off = 1; off < 256; off <<= 1) {
        int t = (tid >= off) ? s[tid - off] : 0;
        __syncthreads();
        s[tid] += t;
        __syncthreads();
    }
    if (gid < N) offsets[gid] = s[tid] - v;   // exclusive
    if (tid == 255) block_sums[blockIdx.x] = s[255];
}

__global__ __launch_bounds__(512) void scan_sums(int* __restrict__ block_sums, int nb)
{
    __shared__ int s[512];
    int tid = threadIdx.x;
    int v = (tid < nb) ? block_sums[tid] : 0;
    s[tid] = v; __syncthreads();
    for (int off = 1; off < 512; off <<= 1) {
        int t = (tid >= off) ? s[tid - off] : 0;
        __syncthreads();
        s[tid] += t;
        __syncthreads();
    }
    if (tid < nb) block_sums[tid] = s[tid] - v;  // exclusive
}

__global__ __launch_bounds__(256) void scan_add(
    int* __restrict__ offsets, const int* __restrict__ block_sums, int N, int E)
{
    int gid = blockIdx.x * 256 + threadIdx.x;
    if (gid < N) offsets[gid] += block_sums[blockIdx.x];
    if (gid == 0) offsets[N] = E;
}

// ---------------- atomic-free CSR scatter --------------------------------------
__global__ __launch_bounds__(256) void scatter_kernel(
    const int* __restrict__ row, const int* __restrict__ col,
    const float* __restrict__ attr, const int* __restrict__ offsets,
    const int* __restrict__ lpos,
    int* __restrict__ col_sorted, float* __restrict__ attr_sorted, int E)
{
    int e = blockIdx.x * 256 + threadIdx.x;
    if (e < E) {
        int p = offsets[row[e]] + lpos[e];
        col_sorted[p] = col[e];
        attr_sorted[p] = attr[e];
    }
}

// ---------------- node transform (MFMA, quadrant + LDS-staged A) ---------------
// Block = 64 nodes (4 M-tiles); wave q converts M-tile q once into LDS, then
// computes col quadrant q of xd (tile q) and agg (tile 4+q).
#define NSLOT(mt, ks, hl) ((((mt) * 2 + (ks)) * 2 + (hl)))
__global__ __launch_bounds__(256) void node_transform_mfma(
    const float* __restrict__ x, const short* __restrict__ frag,
    const float* __restrict__ b, const int* __restrict__ deg,
    float* __restrict__ xd, float* __restrict__ agg, int N)
{
    __shared__ short8 afrag[16 * 64];   // 16 KB
    const int tid = threadIdx.x, lane = tid & 63, q = tid >> 6;
    const int base = blockIdx.x * 64;
    const int arow = lane & 15;
    const int kq = (lane >> 4) * 8;
    const short8* fhi = (const short8*)frag;
    const short8* flo = fhi + 16 * 64;

    // conversion phase: wave q splits its own M-tile
    {
        const int m = base + q * 16 + arow;
#pragma unroll
        for (int ks = 0; ks < 2; ks++) {
            short8 hi, lo;
            if (m < N) split8(x + (size_t)m * H + ks * 32 + kq, hi, lo);
            else       zero8(hi, lo);
            afrag[NSLOT(q, ks, 0) * 64 + lane] = hi;
            afrag[NSLOT(q, ks, 1) * 64 + lane] = lo;
        }
    }
    __syncthreads();

    float4v accd[4], accs[4];
#pragma unroll
    for (int mt = 0; mt < 4; mt++) {
        accd[mt] = (float4v){0.f, 0.f, 0.f, 0.f};
        accs[mt] = (float4v){0.f, 0.f, 0.f, 0.f};
    }

#pragma unroll
    for (int ks = 0; ks < 2; ks++) {
        short8 ah[4], al[4];
#pragma unroll
        for (int mt = 0; mt < 4; mt++) {
            ah[mt] = afrag[NSLOT(mt, ks, 0) * 64 + lane];
            al[mt] = afrag[NSLOT(mt, ks, 1) * 64 + lane];
        }
        const int sd = q * 2 + ks;            // tile q  (xd cols)
        short8 bh = fhi[sd * 64 + lane];
        short8 bl = flo[sd * 64 + lane];
#pragma unroll
        for (int mt = 0; mt < 4; mt++) {
            accd[mt] = MFMA(ah[mt], bh, accd[mt]);
            accd[mt] = MFMA(al[mt], bh, accd[mt]);
            accd[mt] = MFMA(ah[mt], bl, accd[mt]);
        }
        const int ss = (4 + q) * 2 + ks;      // tile 4+q (agg cols)
        short8 ch = fhi[ss * 64 + lane];
        short8 cl = flo[ss * 64 + lane];
#pragma unroll
        for (int mt = 0; mt < 4; mt++) {
            accs[mt] = MFMA(ah[mt], ch, accs[mt]);
            accs[mt] = MFMA(al[mt], ch, accs[mt]);
            accs[mt] = MFMA(ah[mt], cl, accs[mt]);
        }
    }

    const int colb = lane & 15;
    const int rq4 = (lane >> 4) * 4;
    const int j = q * 16 + colb;
    const float bj = b[j];
#pragma unroll
    for (int mt = 0; mt < 4; mt++) {
#pragma unroll
        for (int r = 0; r < 4; r++) {
            const int m = base + mt * 16 + rq4 + r;
            if (m >= N) continue;
            xd[(size_t)m * H + j] = accd[mt][r];
            agg[(size_t)m * H + j] = (float)deg[m] * (accs[mt][r] + bj);
        }
    }
}

// ---------------- gather aggregation (fp32 xd, 4-way ILP) -----------------------
__global__ __launch_bounds__(256) void aggregate(
    const int* __restrict__ offsets, const int* __restrict__ col_sorted,
    const float* __restrict__ attr_sorted, const float* __restrict__ xd,
    const float* __restrict__ W, float* __restrict__ agg, int N)
{
    const int tid = threadIdx.x, lane = tid & 63, wv = tid >> 6;
    const int n = blockIdx.x * 4 + wv;
    if (n >= N) return;
    const float wa = W[(size_t)lane * 129 + 128];
    const int beg = offsets[n], end = offsets[n + 1];
    float acc0 = agg[(size_t)n * H + lane];
    float acc1 = 0.f, acc2 = 0.f, acc3 = 0.f;
    for (int k = beg; k < end; k += 64) {
        int cnt = end - k; if (cnt > 64) cnt = 64;
        int cl = 0; float al = 0.f;
        if (k + lane < end) {
            cl = col_sorted[k + lane];
            al = attr_sorted[k + lane];
        }
        int j = 0;
        for (; j + 4 <= cnt; j += 4) {
            int c0 = __builtin_amdgcn_readlane(cl, j);
            int c1 = __builtin_amdgcn_readlane(cl, j + 1);
            int c2 = __builtin_amdgcn_readlane(cl, j + 2);
            int c3 = __builtin_amdgcn_readlane(cl, j + 3);
            float a0 = lane_bcast(al, j);
            float a1 = lane_bcast(al, j + 1);
            float a2 = lane_bcast(al, j + 2);
            float a3 = lane_bcast(al, j + 3);
            float v0 = xd[(size_t)c0 * H + lane];
            float v1 = xd[(size_t)c1 * H + lane];
            float v2 = xd[(size_t)c2 * H + lane];
            float v3 = xd[(size_t)c3 * H + lane];
            acc0 += fmaf(wa, a0, v0);
            acc1 += fmaf(wa, a1, v1);
            acc2 += fmaf(wa, a2, v2);
            acc3 += fmaf(wa, a3, v3);
        }
        for (; j < cnt; j++) {
            int c = __builtin_amdgcn_readlane(cl, j);
            float a = lane_bcast(al, j);
            acc0 += fmaf(wa, a, xd[(size_t)c * H + lane]);
        }
    }
    agg[(size_t)n * H + lane] = (acc0 + acc1) + (acc2 + acc3);
}

// ---------------- GRU cell (MFMA, quadrant + LDS-staged A) ----------------------
// Block = 64 nodes; wave q converts M-tile q (agg and x) into LDS once, then
// computes gate cols q*16..q*16+15: gi tiles {q,4+q,8+q}, gh {12+q,16+q,20+q}.
#define GSLOT(mt, ks, arr, hl) (((((mt) * 2 + (ks)) * 2 + (arr)) * 2 + (hl)))
__global__ __launch_bounds__(256) void gru_mfma(
    const float* __restrict__ agg, float* __restrict__ x,
    const short* __restrict__ frag,
    const float* __restrict__ bih, const float* __restrict__ bhh, int N)
{
    __shared__ short8 afrag[32 * 64];   // 32 KB
    const int tid = threadIdx.x, lane = tid & 63, q = tid >> 6;
    const int base = blockIdx.x * 64;
    const int arow = lane & 15;
    const int kq = (lane >> 4) * 8;
    const short8* fhi = (const short8*)frag;
    const short8* flo = fhi + 48 * 64;

    // conversion phase: wave q splits its own M-tile (agg + x)
    {
        const int m = base + q * 16 + arow;
#pragma unroll
        for (int ks = 0; ks < 2; ks++) {
            short8 hi, lo;
            if (m < N) split8(agg + (size_t)m * H + ks * 32 + kq, hi, lo);
            else       zero8(hi, lo);
            afrag[GSLOT(q, ks, 0, 0) * 64 + lane] = hi;
            afrag[GSLOT(q, ks, 0, 1) * 64 + lane] = lo;
            if (m < N) split8(x + (size_t)m * H + ks * 32 + kq, hi, lo);
            else       zero8(hi, lo);
            afrag[GSLOT(q, ks, 1, 0) * 64 + lane] = hi;
            afrag[GSLOT(q, ks, 1, 1) * 64 + lane] = lo;
        }
    }
    __syncthreads();
    // NOTE: all global reads of x happened before the barrier; epilogue writes
    // after it, and each wave reads/writes only its own column quadrant.

    float4v acc[6][4];   // [ir,iz,in,hr,hz,hn][M-tile]
#pragma unroll
    for (int g = 0; g < 6; g++)
#pragma unroll
        for (int mt = 0; mt < 4; mt++) acc[g][mt] = (float4v){0.f, 0.f, 0.f, 0.f};

#pragma unroll
    for (int ks = 0; ks < 2; ks++) {
        short8 ah[4], al[4];
        // gi half: A = agg fragments
#pragma unroll
        for (int mt = 0; mt < 4; mt++) {
            ah[mt] = afrag[GSLOT(mt, ks, 0, 0) * 64 + lane];
            al[mt] = afrag[GSLOT(mt, ks, 0, 1) * 64 + lane];
        }
#pragma unroll
        for (int g = 0; g < 3; g++) {
            const int si = (g * 4 + q) * 2 + ks;
            short8 bh = fhi[si * 64 + lane];
            short8 bl = flo[si * 64 + lane];
#pragma unroll
            for (int mt = 0; mt < 4; mt++) {
                acc[g][mt] = MFMA(ah[mt], bh, acc[g][mt]);
                acc[g][mt] = MFMA(al[mt], bh, acc[g][mt]);
                acc[g][mt] = MFMA(ah[mt], bl, acc[g][mt]);
            }
        }
        // gh half: A = x fragments
#pragma unroll
        for (int mt = 0; mt < 4; mt++) {
            ah[mt] = afrag[GSLOT(mt, ks, 1, 0) * 64 + lane];
            al[mt] = afrag[GSLOT(mt, ks, 1, 1) * 64 + lane];
        }
#pragma unroll
        for (int g = 0; g < 3; g++) {
            const int sh = (12 + g * 4 + q) * 2 + ks;
            short8 bh = fhi[sh * 64 + lane];
            short8 bl = flo[sh * 64 + lane];
#pragma unroll
            for (int mt = 0; mt < 4; mt++) {
                acc[3 + g][mt] = MFMA(ah[mt], bh, acc[3 + g][mt]);
                acc[3 + g][mt] = MFMA(al[mt], bh, acc[3 + g][mt]);
                acc[3 + g][mt] = MFMA(ah[mt], bl, acc[3 + g][mt]);
            }
        }
    }

    const int colb = lane & 15;
    const int rq4 = (lane >> 4) * 4;
    const int j = q * 16 + colb;
    const float b_ir = bih[j], b_iz = bih[64 + j], b_in = bih[128 + j];
    const float b_hr = bhh[j], b_hz = bhh[64 + j], b_hn = bhh[128 + j];
#pragma unroll
    for (int mt = 0; mt < 4; mt++) {
#pragma unroll
        for (int r = 0; r < 4; r++) {
            const int m = base + mt * 16 + rq4 + r;
            if (m >= N) continue;
            float ir = acc[0][mt][r] + b_ir;
            float iz = acc[1][mt][r] + b_iz;
            float in_ = acc[2][mt][r] + b_in;
            float hr = acc[3][mt][r] + b_hr;
            float hz = acc[4][mt][r] + b_hz;
            float hn = acc[5][mt][r] + b_hn;
            float rr = 1.f / (1.f + __expf(-(ir + hr)));
            float zz = 1.f / (1.f + __expf(-(iz + hz)));
            float e2 = __expf(2.f * (in_ + rr * hn));
            float nn = 1.f - 2.f / (e2 + 1.f);          // tanh
            float hold = x[(size_t)m * H + j];
            x[(size_t)m * H + j] = (1.f - zz) * nn + zz * hold;
        }
    }
}

extern "C" void kernel_launch(void* const* d_in, const int* in_sizes, int n_in,
                              void* d_out, int out_size, void* d_ws, size_t ws_size,
                              hipStream_t stream) {
    const float* x_in  = (const float*)d_in[0];
    const int*   ei    = (const int*)d_in[1];
    const float* attr  = (const float*)d_in[2];
    const float* msg_W = (const float*)d_in[3];
    const float* msg_b = (const float*)d_in[4];
    const float* Wih   = (const float*)d_in[5];
    const float* bih   = (const float*)d_in[6];
    const float* Whh   = (const float*)d_in[7];
    const float* bhh   = (const float*)d_in[8];

    const int N = in_sizes[0] / H;        // 100000
    const int E = in_sizes[2];            // 1250000
    const int T = in_sizes[4] / H;        // 2
    const int* row = ei;
    const int* col = ei + E;

    // ---- workspace layout ----
    float* x          = (float*)d_out;                    // live node state [N,H]
    float* agg        = (float*)d_ws;                     // [N,H]
    float* xd         = agg + (size_t)N * H;              // [N,H]
    int*   deg        = (int*)(xd + (size_t)N * H);       // [N]
    int*   offsets    = deg + N;                          // [N+1]
    int*   bsums      = offsets + (N + 1);                // [512]
    int*   lpos       = bsums + 512;                      // [E]
    int*   col_sorted = lpos + E;                         // [E]
    float* attr_sorted = (float*)(col_sorted + E);        // [E]
    short* msgfrag    = (short*)(attr_sorted + E);        // [T][16384]
    short* grufrag    = msgfrag + (size_t)T * 16384;      // [T][49152]

    const int nb = (N + 255) / 256;
    const int eb = (E + 255) / 256;

    hipMemcpyAsync(x, x_in, (size_t)N * H * sizeof(float),
                   hipMemcpyDeviceToDevice, stream);
    hipMemsetAsync(deg, 0, (size_t)N * sizeof(int), stream);

    prep_msg<<<T * 16, 64, 0, stream>>>(msg_W, msgfrag);
    prep_gru<<<T * 48, 64, 0, stream>>>(Wih, Whh, grufrag);

    count_kernel<<<eb, 256, 0, stream>>>(row, deg, lpos, E);
    scan_block<<<nb, 256, 0, stream>>>(deg, offsets, bsums, N);
    scan_sums<<<1, 512, 0, stream>>>(bsums, nb);
    scan_add<<<nb, 256, 0, stream>>>(offsets, bsums, N, E);
    scatter_kernel<<<eb, 256, 0, stream>>>(row, col, attr, offsets, lpos,
                                           col_sorted, attr_sorted, E);

    const int nbq = (N + 63) / 64;           // 64 nodes / block (4 waves)
    const int agg_blocks = (N + 3) / 4;      // 4 nodes (waves) / block

    for (int t = 0; t < T; t++) {
        const float* Wt = msg_W + (size_t)t * H * (2 * H + 1);
        node_transform_mfma<<<nbq, 256, 0, stream>>>(
            x, msgfrag + (size_t)t * 16384, msg_b + (size_t)t * H, deg, xd, agg, N);
        aggregate<<<agg_blocks, 256, 0, stream>>>(
            offsets, col_sorted, attr_sorted, xd, Wt, agg, N);
        gru_mfma<<<nbq, 256, 0, stream>>>(
            agg, x, grufrag + (size_t)t * 49152,
            bih + (size_t)t * 3 * H, bhh + (size_t)t * 3 * H, N);
    }
}

// Round 8
// 407.533 us; speedup vs baseline: 1.1445x; 1.0193x over previous
//
#include <hip/hip_runtime.h>
#include <hip/hip_bf16.h>

#define H 64

typedef __attribute__((ext_vector_type(8))) short short8;
typedef __attribute__((ext_vector_type(4))) float float4v;

__device__ __forceinline__ float lane_bcast(float v, int k) {
    return __int_as_float(__builtin_amdgcn_readlane(__float_as_int(v), k));
}
__device__ __forceinline__ short f2bf_bits(float f) {
    union { __hip_bfloat16 b; short s; } u;
    u.b = __float2bfloat16(f);
    return u.s;
}
__device__ __forceinline__ float bf2f(unsigned short s) {
    union { unsigned int u; float f; } v;
    v.u = ((unsigned int)s) << 16;
    return v.f;
}
// split 8 consecutive floats into bf16 hi + lo fragments
__device__ __forceinline__ void split8(const float* __restrict__ p,
                                       short8& hi, short8& lo) {
    float4v f0 = *(const float4v*)p;
    float4v f1 = *(const float4v*)(p + 4);
#pragma unroll
    for (int j = 0; j < 8; j++) {
        float f = (j < 4) ? f0[j] : f1[j - 4];
        short h = f2bf_bits(f);
        float fh = bf2f((unsigned short)h);
        hi[j] = h;
        lo[j] = f2bf_bits(f - fh);
    }
}
__device__ __forceinline__ void zero8(short8& hi, short8& lo) {
#pragma unroll
    for (int j = 0; j < 8; j++) { hi[j] = 0; lo[j] = 0; }
}

#define MFMA(a, b, c) __builtin_amdgcn_mfma_f32_16x16x32_bf16(a, b, c, 0, 0, 0)

// ---------------- weight fragment prep (once per call; shared by all waves) ----
__global__ __launch_bounds__(64) void prep_msg(
    const float* __restrict__ msg_W, short* __restrict__ frag)
{
    const int slot = blockIdx.x & 15, t = blockIdx.x >> 4, lane = threadIdx.x;
    const int tile = slot >> 1, ks = slot & 1;
    const float* W = msg_W + (size_t)t * H * 129;
    const int wrow = (tile & 3) * 16 + (lane & 15);
    const int coff = (tile < 4) ? 0 : 64;
    const int kq = (lane >> 4) * 8;
    short8 hi, lo;
    split8(W + (size_t)wrow * 129 + coff + ks * 32 + kq, hi, lo);
    short8* out = (short8*)(frag + (size_t)t * 16384);
    out[slot * 64 + lane] = hi;
    out[16 * 64 + slot * 64 + lane] = lo;
}

__global__ __launch_bounds__(64) void prep_gru(
    const float* __restrict__ Wih, const float* __restrict__ Whh,
    short* __restrict__ frag)
{
    const int slot = blockIdx.x % 48, t = blockIdx.x / 48, lane = threadIdx.x;
    const int tile = slot >> 1, ks = slot & 1;
    const int kq = (lane >> 4) * 8;
    const float* Wp = (tile < 12)
        ? (Wih + (size_t)t * 192 * H + ((size_t)(tile * 16 + (lane & 15))) * H)
        : (Whh + (size_t)t * 192 * H + ((size_t)((tile - 12) * 16 + (lane & 15))) * H);
    short8 hi, lo;
    split8(Wp + ks * 32 + kq, hi, lo);
    short8* out = (short8*)(frag + (size_t)t * 49152);
    out[slot * 64 + lane] = hi;
    out[48 * 64 + slot * 64 + lane] = lo;
}

// ---------------- count: deg[n] += 1, record local position --------------------
__global__ __launch_bounds__(256) void count_kernel(
    const int* __restrict__ row, int* __restrict__ deg,
    int* __restrict__ lpos, int E)
{
    int e = blockIdx.x * 256 + threadIdx.x;
    if (e < E) lpos[e] = atomicAdd(&deg[row[e]], 1);
}

// ---------------- 3-phase exclusive scan of deg -> offsets ---------------------
__global__ __launch_bounds__(256) void scan_block(
    const int* __restrict__ deg, int* __restrict__ offsets,
    int* __restrict__ block_sums, int N)
{
    __shared__ int s[256];
    int tid = threadIdx.x, gid = blockIdx.x * 256 + tid;
    int v = (gid < N) ? deg[gid] : 0;
    s[tid] = v; __syncthreads();
    for (int off = 1; off < 256; off <<= 1) {
        int t = (tid >= off) ? s[tid - off] : 0;
        __syncthreads();
        s[tid] += t;
        __syncthreads();
    }
    if (gid < N) offsets[gid] = s[tid] - v;   // exclusive
    if (tid == 255) block_sums[blockIdx.x] = s[255];
}

__global__ __launch_bounds__(512) void scan_sums(int* __restrict__ block_sums, int nb)
{
    __shared__ int s[512];
    int tid = threadIdx.x;
    int v = (tid < nb) ? block_sums[tid] : 0;
    s[tid] = v; __syncthreads();
    for (int off = 1; off < 512; off <<= 1) {
        int t = (tid >= off) ? s[tid - off] : 0;
        __syncthreads();
        s[tid] += t;
        __syncthreads();
    }
    if (tid < nb) block_sums[tid] = s[tid] - v;  // exclusive
}

__global__ __launch_bounds__(256) void scan_add(
    int* __restrict__ offsets, const int* __restrict__ block_sums, int N, int E)
{
    int gid = blockIdx.x * 256 + threadIdx.x;
    if (gid < N) offsets[gid] += block_sums[blockIdx.x];
    if (gid == 0) offsets[N] = E;
}

// ---------------- atomic-free CSR scatter (packed int2 payload) ----------------
__global__ __launch_bounds__(256) void scatter_kernel(
    const int* __restrict__ row, const int* __restrict__ col,
    const float* __restrict__ attr, const int* __restrict__ offsets,
    const int* __restrict__ lpos, int2* __restrict__ edata, int E)
{
    int e = blockIdx.x * 256 + threadIdx.x;
    if (e < E) {
        int p = offsets[row[e]] + lpos[e];
        int2 v;
        v.x = col[e];
        v.y = __float_as_int(attr[e]);
        edata[p] = v;
    }
}

// ---------------- node transform (MFMA, quadrant + LDS-staged A) ---------------
#define NSLOT(mt, ks, hl) ((((mt) * 2 + (ks)) * 2 + (hl)))
__global__ __launch_bounds__(256) void node_transform_mfma(
    const float* __restrict__ x, const short* __restrict__ frag,
    const float* __restrict__ b, const int* __restrict__ deg,
    float* __restrict__ xd, float* __restrict__ agg, int N)
{
    __shared__ short8 afrag[16 * 64];   // 16 KB
    const int tid = threadIdx.x, lane = tid & 63, q = tid >> 6;
    const int base = blockIdx.x * 64;
    const int arow = lane & 15;
    const int kq = (lane >> 4) * 8;
    const short8* fhi = (const short8*)frag;
    const short8* flo = fhi + 16 * 64;

    {
        const int m = base + q * 16 + arow;
#pragma unroll
        for (int ks = 0; ks < 2; ks++) {
            short8 hi, lo;
            if (m < N) split8(x + (size_t)m * H + ks * 32 + kq, hi, lo);
            else       zero8(hi, lo);
            afrag[NSLOT(q, ks, 0) * 64 + lane] = hi;
            afrag[NSLOT(q, ks, 1) * 64 + lane] = lo;
        }
    }
    __syncthreads();

    float4v accd[4], accs[4];
#pragma unroll
    for (int mt = 0; mt < 4; mt++) {
        accd[mt] = (float4v){0.f, 0.f, 0.f, 0.f};
        accs[mt] = (float4v){0.f, 0.f, 0.f, 0.f};
    }

#pragma unroll
    for (int ks = 0; ks < 2; ks++) {
        short8 ah[4], al[4];
#pragma unroll
        for (int mt = 0; mt < 4; mt++) {
            ah[mt] = afrag[NSLOT(mt, ks, 0) * 64 + lane];
            al[mt] = afrag[NSLOT(mt, ks, 1) * 64 + lane];
        }
        const int sd = q * 2 + ks;
        short8 bh = fhi[sd * 64 + lane];
        short8 bl = flo[sd * 64 + lane];
#pragma unroll
        for (int mt = 0; mt < 4; mt++) {
            accd[mt] = MFMA(ah[mt], bh, accd[mt]);
            accd[mt] = MFMA(al[mt], bh, accd[mt]);
            accd[mt] = MFMA(ah[mt], bl, accd[mt]);
        }
        const int ss = (4 + q) * 2 + ks;
        short8 ch = fhi[ss * 64 + lane];
        short8 cl = flo[ss * 64 + lane];
#pragma unroll
        for (int mt = 0; mt < 4; mt++) {
            accs[mt] = MFMA(ah[mt], ch, accs[mt]);
            accs[mt] = MFMA(al[mt], ch, accs[mt]);
            accs[mt] = MFMA(ah[mt], cl, accs[mt]);
        }
    }

    const int colb = lane & 15;
    const int rq4 = (lane >> 4) * 4;
    const int j = q * 16 + colb;
    const float bj = b[j];
#pragma unroll
    for (int mt = 0; mt < 4; mt++) {
#pragma unroll
        for (int r = 0; r < 4; r++) {
            const int m = base + mt * 16 + rq4 + r;
            if (m >= N) continue;
            xd[(size_t)m * H + j] = accd[mt][r];
            agg[(size_t)m * H + j] = (float)deg[m] * (accs[mt][r] + bj);
        }
    }
}

// ---------------- gather aggregation (packed edata, 8-deep pipeline) ------------
// agg[n][j] += sum_e ( xd[col_e][j] + wa[j]*attr_e )
__global__ __launch_bounds__(256) void aggregate(
    const int* __restrict__ offsets, const int2* __restrict__ edata,
    const float* __restrict__ xd,
    const float* __restrict__ W, float* __restrict__ agg, int N)
{
    const int tid = threadIdx.x, lane = tid & 63, wv = tid >> 6;
    const int n = blockIdx.x * 4 + wv;
    if (n >= N) return;
    const float wa = W[(size_t)lane * 129 + 128];
    const int beg = offsets[n], end = offsets[n + 1];
    float acc0 = agg[(size_t)n * H + lane];
    float acc1 = 0.f, acc2 = 0.f, acc3 = 0.f;
    for (int k = beg; k < end; k += 64) {
        int cnt = end - k; if (cnt > 64) cnt = 64;
        int2 ed = make_int2(0, 0);
        if (k + lane < end) ed = edata[k + lane];
        int j = 0;
        for (; j + 8 <= cnt; j += 8) {
            float v[8];
#pragma unroll
            for (int u = 0; u < 8; u++) {
                int c = __builtin_amdgcn_readlane(ed.x, j + u);
                v[u] = xd[(size_t)c * H + lane];
            }
#pragma unroll
            for (int u = 0; u < 8; u++) {
                float a = lane_bcast(__int_as_float(ed.y), j + u);
                float t = fmaf(wa, a, v[u]);
                if ((u & 3) == 0) acc0 += t;
                else if ((u & 3) == 1) acc1 += t;
                else if ((u & 3) == 2) acc2 += t;
                else acc3 += t;
            }
        }
        for (; j < cnt; j++) {
            int c = __builtin_amdgcn_readlane(ed.x, j);
            float a = lane_bcast(__int_as_float(ed.y), j);
            acc0 += fmaf(wa, a, xd[(size_t)c * H + lane]);
        }
    }
    agg[(size_t)n * H + lane] = (acc0 + acc1) + (acc2 + acc3);
}

// ---------------- GRU cell (MFMA, quadrant + LDS-staged A) ----------------------
#define GSLOT(mt, ks, arr, hl) (((((mt) * 2 + (ks)) * 2 + (arr)) * 2 + (hl)))
__global__ __launch_bounds__(256) void gru_mfma(
    const float* __restrict__ agg, float* __restrict__ x,
    const short* __restrict__ frag,
    const float* __restrict__ bih, const float* __restrict__ bhh, int N)
{
    __shared__ short8 afrag[32 * 64];   // 32 KB
    const int tid = threadIdx.x, lane = tid & 63, q = tid >> 6;
    const int base = blockIdx.x * 64;
    const int arow = lane & 15;
    const int kq = (lane >> 4) * 8;
    const short8* fhi = (const short8*)frag;
    const short8* flo = fhi + 48 * 64;

    {
        const int m = base + q * 16 + arow;
#pragma unroll
        for (int ks = 0; ks < 2; ks++) {
            short8 hi, lo;
            if (m < N) split8(agg + (size_t)m * H + ks * 32 + kq, hi, lo);
            else       zero8(hi, lo);
            afrag[GSLOT(q, ks, 0, 0) * 64 + lane] = hi;
            afrag[GSLOT(q, ks, 0, 1) * 64 + lane] = lo;
            if (m < N) split8(x + (size_t)m * H + ks * 32 + kq, hi, lo);
            else       zero8(hi, lo);
            afrag[GSLOT(q, ks, 1, 0) * 64 + lane] = hi;
            afrag[GSLOT(q, ks, 1, 1) * 64 + lane] = lo;
        }
    }
    __syncthreads();
    // all global reads of x precede the barrier; epilogue writes after it.

    float4v acc[6][4];
#pragma unroll
    for (int g = 0; g < 6; g++)
#pragma unroll
        for (int mt = 0; mt < 4; mt++) acc[g][mt] = (float4v){0.f, 0.f, 0.f, 0.f};

#pragma unroll
    for (int ks = 0; ks < 2; ks++) {
        short8 ah[4], al[4];
#pragma unroll
        for (int mt = 0; mt < 4; mt++) {
            ah[mt] = afrag[GSLOT(mt, ks, 0, 0) * 64 + lane];
            al[mt] = afrag[GSLOT(mt, ks, 0, 1) * 64 + lane];
        }
#pragma unroll
        for (int g = 0; g < 3; g++) {
            const int si = (g * 4 + q) * 2 + ks;
            short8 bh = fhi[si * 64 + lane];
            short8 bl = flo[si * 64 + lane];
#pragma unroll
            for (int mt = 0; mt < 4; mt++) {
                acc[g][mt] = MFMA(ah[mt], bh, acc[g][mt]);
                acc[g][mt] = MFMA(al[mt], bh, acc[g][mt]);
                acc[g][mt] = MFMA(ah[mt], bl, acc[g][mt]);
            }
        }
#pragma unroll
        for (int mt = 0; mt < 4; mt++) {
            ah[mt] = afrag[GSLOT(mt, ks, 1, 0) * 64 + lane];
            al[mt] = afrag[GSLOT(mt, ks, 1, 1) * 64 + lane];
        }
#pragma unroll
        for (int g = 0; g < 3; g++) {
            const int sh = (12 + g * 4 + q) * 2 + ks;
            short8 bh = fhi[sh * 64 + lane];
            short8 bl = flo[sh * 64 + lane];
#pragma unroll
            for (int mt = 0; mt < 4; mt++) {
                acc[3 + g][mt] = MFMA(ah[mt], bh, acc[3 + g][mt]);
                acc[3 + g][mt] = MFMA(al[mt], bh, acc[3 + g][mt]);
                acc[3 + g][mt] = MFMA(ah[mt], bl, acc[3 + g][mt]);
            }
        }
    }

    const int colb = lane & 15;
    const int rq4 = (lane >> 4) * 4;
    const int j = q * 16 + colb;
    const float b_ir = bih[j], b_iz = bih[64 + j], b_in = bih[128 + j];
    const float b_hr = bhh[j], b_hz = bhh[64 + j], b_hn = bhh[128 + j];
#pragma unroll
    for (int mt = 0; mt < 4; mt++) {
#pragma unroll
        for (int r = 0; r < 4; r++) {
            const int m = base + mt * 16 + rq4 + r;
            if (m >= N) continue;
            float ir = acc[0][mt][r] + b_ir;
            float iz = acc[1][mt][r] + b_iz;
            float in_ = acc[2][mt][r] + b_in;
            float hr = acc[3][mt][r] + b_hr;
            float hz = acc[4][mt][r] + b_hz;
            float hn = acc[5][mt][r] + b_hn;
            float rr = 1.f / (1.f + __expf(-(ir + hr)));
            float zz = 1.f / (1.f + __expf(-(iz + hz)));
            float e2 = __expf(2.f * (in_ + rr * hn));
            float nn = 1.f - 2.f / (e2 + 1.f);          // tanh
            float hold = x[(size_t)m * H + j];
            x[(size_t)m * H + j] = (1.f - zz) * nn + zz * hold;
        }
    }
}

extern "C" void kernel_launch(void* const* d_in, const int* in_sizes, int n_in,
                              void* d_out, int out_size, void* d_ws, size_t ws_size,
                              hipStream_t stream) {
    const float* x_in  = (const float*)d_in[0];
    const int*   ei    = (const int*)d_in[1];
    const float* attr  = (const float*)d_in[2];
    const float* msg_W = (const float*)d_in[3];
    const float* msg_b = (const float*)d_in[4];
    const float* Wih   = (const float*)d_in[5];
    const float* bih   = (const float*)d_in[6];
    const float* Whh   = (const float*)d_in[7];
    const float* bhh   = (const float*)d_in[8];

    const int N = in_sizes[0] / H;        // 100000
    const int E = in_sizes[2];            // 1250000
    const int T = in_sizes[4] / H;        // 2
    const int* row = ei;
    const int* col = ei + E;

    // ---- workspace layout ----
    float* x          = (float*)d_out;                    // live node state [N,H]
    float* agg        = (float*)d_ws;                     // [N,H]
    float* xd         = agg + (size_t)N * H;              // [N,H]
    int*   deg        = (int*)(xd + (size_t)N * H);       // [N]
    int*   offsets    = deg + N;                          // [N+1]
    int*   bsums      = offsets + (N + 1);                // [512]
    int*   lpos       = bsums + 512;                      // [E]
    int2*  edata      = (int2*)(lpos + E);                // [E] packed (col, attr)
    short* msgfrag    = (short*)(edata + E);              // [T][16384]
    short* grufrag    = msgfrag + (size_t)T * 16384;      // [T][49152]

    const int nb = (N + 255) / 256;
    const int eb = (E + 255) / 256;

    hipMemcpyAsync(x, x_in, (size_t)N * H * sizeof(float),
                   hipMemcpyDeviceToDevice, stream);
    hipMemsetAsync(deg, 0, (size_t)N * sizeof(int), stream);

    prep_msg<<<T * 16, 64, 0, stream>>>(msg_W, msgfrag);
    prep_gru<<<T * 48, 64, 0, stream>>>(Wih, Whh, grufrag);

    count_kernel<<<eb, 256, 0, stream>>>(row, deg, lpos, E);
    scan_block<<<nb, 256, 0, stream>>>(deg, offsets, bsums, N);
    scan_sums<<<1, 512, 0, stream>>>(bsums, nb);
    scan_add<<<nb, 256, 0, stream>>>(offsets, bsums, N, E);
    scatter_kernel<<<eb, 256, 0, stream>>>(row, col, attr, offsets, lpos,
                                           edata, E);

    const int nbq = (N + 63) / 64;           // 64 nodes / block (4 waves)
    const int agg_blocks = (N + 3) / 4;      // 4 nodes (waves) / block

    for (int t = 0; t < T; t++) {
        const float* Wt = msg_W + (size_t)t * H * (2 * H + 1);
        node_transform_mfma<<<nbq, 256, 0, stream>>>(
            x, msgfrag + (size_t)t * 16384, msg_b + (size_t)t * H, deg, xd, agg, N);
        aggregate<<<agg_blocks, 256, 0, stream>>>(
            offsets, edata, xd, Wt, agg, N);
        gru_mfma<<<nbq, 256, 0, stream>>>(
            agg, x, grufrag + (size_t)t * 49152,
            bih + (size_t)t * 3 * H, bhh + (size_t)t * 3 * H, N);
    }
}

// Round 9
// 385.166 us; speedup vs baseline: 1.2110x; 1.0581x over previous
//
#include <hip/hip_runtime.h>
#include <hip/hip_bf16.h>
#include <hip/hip_fp16.h>

#define H 64

typedef __attribute__((ext_vector_type(8))) short short8;
typedef __attribute__((ext_vector_type(4))) float float4v;

__device__ __forceinline__ float lane_bcast(float v, int k) {
    return __int_as_float(__builtin_amdgcn_readlane(__float_as_int(v), k));
}
__device__ __forceinline__ short f2bf_bits(float f) {
    union { __hip_bfloat16 b; short s; } u;
    u.b = __float2bfloat16(f);
    return u.s;
}
__device__ __forceinline__ float bf2f(unsigned short s) {
    union { unsigned int u; float f; } v;
    v.u = ((unsigned int)s) << 16;
    return v.f;
}
// split 8 consecutive floats into bf16 hi + lo fragments
__device__ __forceinline__ void split8(const float* __restrict__ p,
                                       short8& hi, short8& lo) {
    float4v f0 = *(const float4v*)p;
    float4v f1 = *(const float4v*)(p + 4);
#pragma unroll
    for (int j = 0; j < 8; j++) {
        float f = (j < 4) ? f0[j] : f1[j - 4];
        short h = f2bf_bits(f);
        float fh = bf2f((unsigned short)h);
        hi[j] = h;
        lo[j] = f2bf_bits(f - fh);
    }
}
__device__ __forceinline__ void zero8(short8& hi, short8& lo) {
#pragma unroll
    for (int j = 0; j < 8; j++) { hi[j] = 0; lo[j] = 0; }
}

#define MFMA(a, b, c) __builtin_amdgcn_mfma_f32_16x16x32_bf16(a, b, c, 0, 0, 0)

// ---------------- weight fragment prep (once per call; shared by all waves) ----
__global__ __launch_bounds__(64) void prep_msg(
    const float* __restrict__ msg_W, short* __restrict__ frag)
{
    const int slot = blockIdx.x & 15, t = blockIdx.x >> 4, lane = threadIdx.x;
    const int tile = slot >> 1, ks = slot & 1;
    const float* W = msg_W + (size_t)t * H * 129;
    const int wrow = (tile & 3) * 16 + (lane & 15);
    const int coff = (tile < 4) ? 0 : 64;
    const int kq = (lane >> 4) * 8;
    short8 hi, lo;
    split8(W + (size_t)wrow * 129 + coff + ks * 32 + kq, hi, lo);
    short8* out = (short8*)(frag + (size_t)t * 16384);
    out[slot * 64 + lane] = hi;
    out[16 * 64 + slot * 64 + lane] = lo;
}

__global__ __launch_bounds__(64) void prep_gru(
    const float* __restrict__ Wih, const float* __restrict__ Whh,
    short* __restrict__ frag)
{
    const int slot = blockIdx.x % 48, t = blockIdx.x / 48, lane = threadIdx.x;
    const int tile = slot >> 1, ks = slot & 1;
    const int kq = (lane >> 4) * 8;
    const float* Wp = (tile < 12)
        ? (Wih + (size_t)t * 192 * H + ((size_t)(tile * 16 + (lane & 15))) * H)
        : (Whh + (size_t)t * 192 * H + ((size_t)((tile - 12) * 16 + (lane & 15))) * H);
    short8 hi, lo;
    split8(Wp + ks * 32 + kq, hi, lo);
    short8* out = (short8*)(frag + (size_t)t * 49152);
    out[slot * 64 + lane] = hi;
    out[48 * 64 + slot * 64 + lane] = lo;
}

// ---------------- count: deg[n] += 1, record local position --------------------
__global__ __launch_bounds__(256) void count_kernel(
    const int* __restrict__ row, int* __restrict__ deg,
    int* __restrict__ lpos, int E)
{
    int e = blockIdx.x * 256 + threadIdx.x;
    if (e < E) lpos[e] = atomicAdd(&deg[row[e]], 1);
}

// ---------------- 3-phase exclusive scan of deg -> offsets ---------------------
__global__ __launch_bounds__(256) void scan_block(
    const int* __restrict__ deg, int* __restrict__ offsets,
    int* __restrict__ block_sums, int N)
{
    __shared__ int s[256];
    int tid = threadIdx.x, gid = blockIdx.x * 256 + tid;
    int v = (gid < N) ? deg[gid] : 0;
    s[tid] = v; __syncthreads();
    for (int off = 1; off < 256; off <<= 1) {
        int t = (tid >= off) ? s[tid - off] : 0;
        __syncthreads();
        s[tid] += t;
        __syncthreads();
    }
    if (gid < N) offsets[gid] = s[tid] - v;   // exclusive
    if (tid == 255) block_sums[blockIdx.x] = s[255];
}

__global__ __launch_bounds__(512) void scan_sums(int* __restrict__ block_sums, int nb)
{
    __shared__ int s[512];
    int tid = threadIdx.x;
    int v = (tid < nb) ? block_sums[tid] : 0;
    s[tid] = v; __syncthreads();
    for (int off = 1; off < 512; off <<= 1) {
        int t = (tid >= off) ? s[tid - off] : 0;
        __syncthreads();
        s[tid] += t;
        __syncthreads();
    }
    if (tid < nb) block_sums[tid] = s[tid] - v;  // exclusive
}

__global__ __launch_bounds__(256) void scan_add(
    int* __restrict__ offsets, const int* __restrict__ block_sums, int N, int E)
{
    int gid = blockIdx.x * 256 + threadIdx.x;
    if (gid < N) offsets[gid] += block_sums[blockIdx.x];
    if (gid == 0) offsets[N] = E;
}

// ---------------- atomic-free CSR scatter (packed int2 payload) ----------------
__global__ __launch_bounds__(256) void scatter_kernel(
    const int* __restrict__ row, const int* __restrict__ col,
    const float* __restrict__ attr, const int* __restrict__ offsets,
    const int* __restrict__ lpos, int2* __restrict__ edata, int E)
{
    int e = blockIdx.x * 256 + threadIdx.x;
    if (e < E) {
        int p = offsets[row[e]] + lpos[e];
        int2 v;
        v.x = col[e];
        v.y = __float_as_int(attr[e]);
        edata[p] = v;
    }
}

// ---------------- node transform (MFMA, quadrant + LDS-staged A) ---------------
#define NSLOT(mt, ks, hl) ((((mt) * 2 + (ks)) * 2 + (hl)))
__global__ __launch_bounds__(256) void node_transform_mfma(
    const float* __restrict__ x, const short* __restrict__ frag,
    const float* __restrict__ b, const int* __restrict__ deg,
    __half* __restrict__ xd, float* __restrict__ agg, int N)
{
    __shared__ short8 afrag[16 * 64];   // 16 KB
    const int tid = threadIdx.x, lane = tid & 63, q = tid >> 6;
    const int base = blockIdx.x * 64;
    const int arow = lane & 15;
    const int kq = (lane >> 4) * 8;
    const short8* fhi = (const short8*)frag;
    const short8* flo = fhi + 16 * 64;

    {
        const int m = base + q * 16 + arow;
#pragma unroll
        for (int ks = 0; ks < 2; ks++) {
            short8 hi, lo;
            if (m < N) split8(x + (size_t)m * H + ks * 32 + kq, hi, lo);
            else       zero8(hi, lo);
            afrag[NSLOT(q, ks, 0) * 64 + lane] = hi;
            afrag[NSLOT(q, ks, 1) * 64 + lane] = lo;
        }
    }
    __syncthreads();

    float4v accd[4], accs[4];
#pragma unroll
    for (int mt = 0; mt < 4; mt++) {
        accd[mt] = (float4v){0.f, 0.f, 0.f, 0.f};
        accs[mt] = (float4v){0.f, 0.f, 0.f, 0.f};
    }

#pragma unroll
    for (int ks = 0; ks < 2; ks++) {
        short8 ah[4], al[4];
#pragma unroll
        for (int mt = 0; mt < 4; mt++) {
            ah[mt] = afrag[NSLOT(mt, ks, 0) * 64 + lane];
            al[mt] = afrag[NSLOT(mt, ks, 1) * 64 + lane];
        }
        const int sd = q * 2 + ks;
        short8 bh = fhi[sd * 64 + lane];
        short8 bl = flo[sd * 64 + lane];
#pragma unroll
        for (int mt = 0; mt < 4; mt++) {
            accd[mt] = MFMA(ah[mt], bh, accd[mt]);
            accd[mt] = MFMA(al[mt], bh, accd[mt]);
            accd[mt] = MFMA(ah[mt], bl, accd[mt]);
        }
        const int ss = (4 + q) * 2 + ks;
        short8 ch = fhi[ss * 64 + lane];
        short8 cl = flo[ss * 64 + lane];
#pragma unroll
        for (int mt = 0; mt < 4; mt++) {
            accs[mt] = MFMA(ah[mt], ch, accs[mt]);
            accs[mt] = MFMA(al[mt], ch, accs[mt]);
            accs[mt] = MFMA(ah[mt], cl, accs[mt]);
        }
    }

    const int colb = lane & 15;
    const int rq4 = (lane >> 4) * 4;
    const int j = q * 16 + colb;
    const float bj = b[j];
#pragma unroll
    for (int mt = 0; mt < 4; mt++) {
#pragma unroll
        for (int r = 0; r < 4; r++) {
            const int m = base + mt * 16 + rq4 + r;
            if (m >= N) continue;
            xd[(size_t)m * H + j] = __float2half(accd[mt][r]);
            agg[(size_t)m * H + j] = (float)deg[m] * (accs[mt][r] + bj);
        }
    }
}

// ---------------- gather aggregation (fp16 xd, 8-deep pipeline) -----------------
// agg[n][j] += sum_e ( xd[col_e][j] + wa[j]*attr_e )
__global__ __launch_bounds__(256) void aggregate(
    const int* __restrict__ offsets, const int2* __restrict__ edata,
    const __half* __restrict__ xd,
    const float* __restrict__ W, float* __restrict__ agg, int N)
{
    const int tid = threadIdx.x, lane = tid & 63, wv = tid >> 6;
    const int n = blockIdx.x * 4 + wv;
    if (n >= N) return;
    const float wa = W[(size_t)lane * 129 + 128];
    const int beg = offsets[n], end = offsets[n + 1];
    float acc0 = agg[(size_t)n * H + lane];
    float acc1 = 0.f, acc2 = 0.f, acc3 = 0.f;
    for (int k = beg; k < end; k += 64) {
        int cnt = end - k; if (cnt > 64) cnt = 64;
        int2 ed = make_int2(0, 0);
        if (k + lane < end) ed = edata[k + lane];
        int j = 0;
        for (; j + 8 <= cnt; j += 8) {
            float v[8];
#pragma unroll
            for (int u = 0; u < 8; u++) {
                int c = __builtin_amdgcn_readlane(ed.x, j + u);
                v[u] = __half2float(xd[(size_t)c * H + lane]);
            }
#pragma unroll
            for (int u = 0; u < 8; u++) {
                float a = lane_bcast(__int_as_float(ed.y), j + u);
                float t = fmaf(wa, a, v[u]);
                if ((u & 3) == 0) acc0 += t;
                else if ((u & 3) == 1) acc1 += t;
                else if ((u & 3) == 2) acc2 += t;
                else acc3 += t;
            }
        }
        for (; j < cnt; j++) {
            int c = __builtin_amdgcn_readlane(ed.x, j);
            float a = lane_bcast(__int_as_float(ed.y), j);
            acc0 += fmaf(wa, a, __half2float(xd[(size_t)c * H + lane]));
        }
    }
    agg[(size_t)n * H + lane] = (acc0 + acc1) + (acc2 + acc3);
}

// ---------------- GRU cell (MFMA, quadrant + LDS-staged A) ----------------------
#define GSLOT(mt, ks, arr, hl) (((((mt) * 2 + (ks)) * 2 + (arr)) * 2 + (hl)))
__global__ __launch_bounds__(256) void gru_mfma(
    const float* __restrict__ agg, float* __restrict__ x,
    const short* __restrict__ frag,
    const float* __restrict__ bih, const float* __restrict__ bhh, int N)
{
    __shared__ short8 afrag[32 * 64];   // 32 KB
    const int tid = threadIdx.x, lane = tid & 63, q = tid >> 6;
    const int base = blockIdx.x * 64;
    const int arow = lane & 15;
    const int kq = (lane >> 4) * 8;
    const short8* fhi = (const short8*)frag;
    const short8* flo = fhi + 48 * 64;

    {
        const int m = base + q * 16 + arow;
#pragma unroll
        for (int ks = 0; ks < 2; ks++) {
            short8 hi, lo;
            if (m < N) split8(agg + (size_t)m * H + ks * 32 + kq, hi, lo);
            else       zero8(hi, lo);
            afrag[GSLOT(q, ks, 0, 0) * 64 + lane] = hi;
            afrag[GSLOT(q, ks, 0, 1) * 64 + lane] = lo;
            if (m < N) split8(x + (size_t)m * H + ks * 32 + kq, hi, lo);
            else       zero8(hi, lo);
            afrag[GSLOT(q, ks, 1, 0) * 64 + lane] = hi;
            afrag[GSLOT(q, ks, 1, 1) * 64 + lane] = lo;
        }
    }
    __syncthreads();
    // all global reads of x precede the barrier; epilogue writes after it.

    float4v acc[6][4];
#pragma unroll
    for (int g = 0; g < 6; g++)
#pragma unroll
        for (int mt = 0; mt < 4; mt++) acc[g][mt] = (float4v){0.f, 0.f, 0.f, 0.f};

#pragma unroll
    for (int ks = 0; ks < 2; ks++) {
        short8 ah[4], al[4];
#pragma unroll
        for (int mt = 0; mt < 4; mt++) {
            ah[mt] = afrag[GSLOT(mt, ks, 0, 0) * 64 + lane];
            al[mt] = afrag[GSLOT(mt, ks, 0, 1) * 64 + lane];
        }
#pragma unroll
        for (int g = 0; g < 3; g++) {
            const int si = (g * 4 + q) * 2 + ks;
            short8 bh = fhi[si * 64 + lane];
            short8 bl = flo[si * 64 + lane];
#pragma unroll
            for (int mt = 0; mt < 4; mt++) {
                acc[g][mt] = MFMA(ah[mt], bh, acc[g][mt]);
                acc[g][mt] = MFMA(al[mt], bh, acc[g][mt]);
                acc[g][mt] = MFMA(ah[mt], bl, acc[g][mt]);
            }
        }
#pragma unroll
        for (int mt = 0; mt < 4; mt++) {
            ah[mt] = afrag[GSLOT(mt, ks, 1, 0) * 64 + lane];
            al[mt] = afrag[GSLOT(mt, ks, 1, 1) * 64 + lane];
        }
#pragma unroll
        for (int g = 0; g < 3; g++) {
            const int sh = (12 + g * 4 + q) * 2 + ks;
            short8 bh = fhi[sh * 64 + lane];
            short8 bl = flo[sh * 64 + lane];
#pragma unroll
            for (int mt = 0; mt < 4; mt++) {
                acc[3 + g][mt] = MFMA(ah[mt], bh, acc[3 + g][mt]);
                acc[3 + g][mt] = MFMA(al[mt], bh, acc[3 + g][mt]);
                acc[3 + g][mt] = MFMA(ah[mt], bl, acc[3 + g][mt]);
            }
        }
    }

    const int colb = lane & 15;
    const int rq4 = (lane >> 4) * 4;
    const int j = q * 16 + colb;
    const float b_ir = bih[j], b_iz = bih[64 + j], b_in = bih[128 + j];
    const float b_hr = bhh[j], b_hz = bhh[64 + j], b_hn = bhh[128 + j];
#pragma unroll
    for (int mt = 0; mt < 4; mt++) {
#pragma unroll
        for (int r = 0; r < 4; r++) {
            const int m = base + mt * 16 + rq4 + r;
            if (m >= N) continue;
            float ir = acc[0][mt][r] + b_ir;
            float iz = acc[1][mt][r] + b_iz;
            float in_ = acc[2][mt][r] + b_in;
            float hr = acc[3][mt][r] + b_hr;
            float hz = acc[4][mt][r] + b_hz;
            float hn = acc[5][mt][r] + b_hn;
            float rr = 1.f / (1.f + __expf(-(ir + hr)));
            float zz = 1.f / (1.f + __expf(-(iz + hz)));
            float e2 = __expf(2.f * (in_ + rr * hn));
            float nn = 1.f - 2.f / (e2 + 1.f);          // tanh
            float hold = x[(size_t)m * H + j];
            x[(size_t)m * H + j] = (1.f - zz) * nn + zz * hold;
        }
    }
}

extern "C" void kernel_launch(void* const* d_in, const int* in_sizes, int n_in,
                              void* d_out, int out_size, void* d_ws, size_t ws_size,
                              hipStream_t stream) {
    const float* x_in  = (const float*)d_in[0];
    const int*   ei    = (const int*)d_in[1];
    const float* attr  = (const float*)d_in[2];
    const float* msg_W = (const float*)d_in[3];
    const float* msg_b = (const float*)d_in[4];
    const float* Wih   = (const float*)d_in[5];
    const float* bih   = (const float*)d_in[6];
    const float* Whh   = (const float*)d_in[7];
    const float* bhh   = (const float*)d_in[8];

    const int N = in_sizes[0] / H;        // 100000
    const int E = in_sizes[2];            // 1250000
    const int T = in_sizes[4] / H;        // 2
    const int* row = ei;
    const int* col = ei + E;

    // ---- workspace layout ----
    float* x          = (float*)d_out;                    // live node state [N,H]
    float* agg        = (float*)d_ws;                     // [N,H] f32
    __half* xd        = (__half*)(agg + (size_t)N * H);   // [N,H] fp16
    int*   deg        = (int*)(xd + (size_t)N * H);       // [N]
    int*   offsets    = deg + N;                          // [N+1]
    int*   bsums      = offsets + (N + 1);                // [512]
    int*   lpos       = bsums + 512;                      // [E]
    int2*  edata      = (int2*)(lpos + E);                // [E] packed (col, attr)
    short* msgfrag    = (short*)(edata + E);              // [T][16384]
    short* grufrag    = msgfrag + (size_t)T * 16384;      // [T][49152]

    const int nb = (N + 255) / 256;
    const int eb = (E + 255) / 256;

    hipMemcpyAsync(x, x_in, (size_t)N * H * sizeof(float),
                   hipMemcpyDeviceToDevice, stream);
    hipMemsetAsync(deg, 0, (size_t)N * sizeof(int), stream);

    prep_msg<<<T * 16, 64, 0, stream>>>(msg_W, msgfrag);
    prep_gru<<<T * 48, 64, 0, stream>>>(Wih, Whh, grufrag);

    count_kernel<<<eb, 256, 0, stream>>>(row, deg, lpos, E);
    scan_block<<<nb, 256, 0, stream>>>(deg, offsets, bsums, N);
    scan_sums<<<1, 512, 0, stream>>>(bsums, nb);
    scan_add<<<nb, 256, 0, stream>>>(offsets, bsums, N, E);
    scatter_kernel<<<eb, 256, 0, stream>>>(row, col, attr, offsets, lpos,
                                           edata, E);

    const int nbq = (N + 63) / 64;           // 64 nodes / block (4 waves)
    const int agg_blocks = (N + 3) / 4;      // 4 nodes (waves) / block

    for (int t = 0; t < T; t++) {
        const float* Wt = msg_W + (size_t)t * H * (2 * H + 1);
        node_transform_mfma<<<nbq, 256, 0, stream>>>(
            x, msgfrag + (size_t)t * 16384, msg_b + (size_t)t * H, deg, xd, agg, N);
        aggregate<<<agg_blocks, 256, 0, stream>>>(
            offsets, edata, xd, Wt, agg, N);
        gru_mfma<<<nbq, 256, 0, stream>>>(
            agg, x, grufrag + (size_t)t * 49152,
            bih + (size_t)t * 3 * H, bhh + (size_t)t * 3 * H, N);
    }
}